// Round 8
// baseline (27.477 us; speedup 1.0000x reference)
//
#include <hip/hip_runtime.h>
#include <math.h>

// Problem constants (from reference init)
#define NB     16      // N
#define PB     4       // P
#define LTAPS  16      // L
#define SS     128     // S = Ns + N_pilot
#define MM     1024    // Mk = OPT_M

#define TWO_PI_F 6.28318530717958647692f

#define HT_BLKS     256                  // 256*256 = 65536 = NB*PB*MM (run FIRST)
#define STREAM_BLKS 2048                 // 2048 blocks * 2048 float4 = TOT4
#define TOT4 (NB * PB * SS * MM / 2)     // 4194304 float4

typedef float f32x4 __attribute__((ext_vector_type(4)));

// ---------------------------------------------------------------------------
// Single fused kernel, HT blocks FIRST so their VALU-bound work overlaps the
// memory-bound streaming blocks instead of forming a serialized tail.
//
//  blocks [0, HT_BLKS):  H_t[np,k] = sum_l cof[l] * w^l, w = exp(-2pi*i*k/M)
//  blocks [HT_BLKS, +STREAM_BLKS): contiguous 2048-float4 chunk per block.
//      Loads: nontemporal (read-once, keep L2 clean).
//      Stores: PLAIN (allocate in L2 -> writes drain lazily; up to ~L2-size
//      of tail writes can remain in flight at end-of-dispatch).
// ---------------------------------------------------------------------------
__global__ __launch_bounds__(256, 8) void fused_kernel(
    const float* __restrict__ in,   // (N,P,S*M,2) f32
    const float* __restrict__ cof,  // (N,P,L)    f32, strictly positive
    float* __restrict__ out,        // (N,P,S*M,2) f32
    float* __restrict__ ht)         // (N,P,M,2)  f32
{
    const int b = blockIdx.x;
    const int t = threadIdx.x;

    if (b >= HT_BLKS) {
        const int sb = b - HT_BLKS;              // streaming block id
        const f32x4* __restrict__ in4  = (const f32x4*)in + (size_t)sb * 2048;
        f32x4* __restrict__       out4 = (f32x4*)out      + (size_t)sb * 2048;

        // ---- issue all 8 loads first (independent of factor preamble) ----
        f32x4 v[8];
#pragma unroll
        for (int k = 0; k < 8; ++k)
            v[k] = __builtin_nontemporal_load(&in4[k * 256 + t]);

        // ---- per-wave redundant factor computation (barrier-free) ----
        const int lane = t & 63;
        const int j    = lane >> 4;              // which of the 4 (np,s) rows
        const int l    = lane & 15;              // tap index
        const int id   = sb * 4 + j;             // flattened (np,s), < 8192
        const int np   = id >> 7;
        const int s    = id & (SS - 1);
        const float cofl   = cof[np * LTAPS + l];
        const float delay1 = (-100.0f / 3.0e8f) * __logf(cofl);
        const float delay2 = (0.0005f / 14.0f) * (float)s;
        const float pc     = TWO_PI_F * 1000.0f * __cosf((TWO_PI_F / 15.0f) * (float)l);
        const float ph     = pc * (delay1 + delay2);
        float sn, cs;
        __sincosf(ph, &sn, &cs);
        float re = cofl * cs;
        float im = -cofl * sn;
#pragma unroll
        for (int w = 1; w < 16; w <<= 1) {       // 16-tap reduce per group
            re += __shfl_xor(re, w);
            im += __shfl_xor(im, w);
        }
        float fre[4], fim[4];
#pragma unroll
        for (int jj = 0; jj < 4; ++jj) {         // broadcast 4 group sums
            fre[jj] = __shfl(re, jj * 16);
            fim[jj] = __shfl(im, jj * 16);
        }

        // ---- multiply + store (plain stores -> L2 write buffering) ----
#pragma unroll
        for (int k = 0; k < 8; ++k) {
            const int jj = k >> 1;               // 512 float4 per (np,s)
            f32x4 r;
            r.x = v[k].x * fre[jj] - v[k].y * fim[jj];
            r.y = v[k].x * fim[jj] + v[k].y * fre[jj];
            r.z = v[k].z * fre[jj] - v[k].w * fim[jj];
            r.w = v[k].z * fim[jj] + v[k].w * fre[jj];
            out4[k * 256 + t] = r;
        }
    } else {
        const int id = b * 256 + t;              // (np, k)
        const int np = id >> 10;
        const int k  = id & (MM - 1);
        float sn, cs;
        __sincosf((TWO_PI_F / (float)MM) * (float)k, &sn, &cs);
        const float wr = cs, wi = -sn;           // w = exp(-2*pi*i*k/M)
        const float* __restrict__ c = cof + np * LTAPS;
        float hr = 0.0f, hi = 0.0f;              // H accumulator
        float cr = 1.0f, ci = 0.0f;              // w^l
#pragma unroll
        for (int l = 0; l < LTAPS; ++l) {
            const float cl = c[l];
            hr += cl * cr;
            hi += cl * ci;
            const float nr = cr * wr - ci * wi;
            const float ni = cr * wi + ci * wr;
            cr = nr; ci = ni;
        }
        float2* __restrict__ o = (float2*)ht;
        o[id] = make_float2(hr, hi);
    }
}

// ---------------------------------------------------------------------------
extern "C" void kernel_launch(void* const* d_in, const int* in_sizes, int n_in,
                              void* d_out, int out_size, void* d_ws, size_t ws_size,
                              hipStream_t stream)
{
    const float* in  = (const float*)d_in[0];   // input_ri (N,P,S*M,2)
    const float* cof = (const float*)d_in[1];   // cof (N,P,L)
    float* out = (float*)d_out;                              // out_ri first
    float* ht  = out + (size_t)NB * PB * SS * MM * 2;        // then H_t_ri

    hipLaunchKernelGGL(fused_kernel, dim3(HT_BLKS + STREAM_BLKS), dim3(256), 0, stream,
                       in, cof, out, ht);
}

// Round 9
// 25.713 us; speedup vs baseline: 1.0686x; 1.0686x over previous
//
#include <hip/hip_runtime.h>
#include <math.h>

// Problem constants (from reference init)
#define NB     16      // N
#define PB     4       // P
#define LTAPS  16      // L
#define SS     128     // S = Ns + N_pilot
#define MM     1024    // Mk = OPT_M

#define TWO_PI_F 6.28318530717958647692f

#define HT_BLKS     256                  // 256*256 = 65536 = NB*PB*MM (run FIRST)
#define STREAM_BLKS 2048                 // 2048 blocks * 2048 float4 = TOT4
#define TOT4 (NB * PB * SS * MM / 2)     // 4194304 float4

typedef float f32x4 __attribute__((ext_vector_type(4)));

// ---------------------------------------------------------------------------
// BEST CONFIG (round 6 revert): single fused kernel, HT blocks FIRST so their
// VALU-bound work overlaps the memory-bound streaming blocks.
//
//  blocks [0, HT_BLKS):  H_t[np,k] = sum_l cof[l] * w^l, w = exp(-2pi*i*k/M)
//      (1 sincos + 15 complex FMAs via power recurrence)
//  blocks [HT_BLKS, +STREAM_BLKS): contiguous 2048-float4 chunk per block
//      = 4 consecutive (np,s) rows. All 8 nontemporal loads issued FIRST;
//      factors computed redundantly per-wave via __shfl reduce (no LDS, no
//      barriers); nontemporal stores (A/B'd vs plain in R8: NT wins by 1.9us).
// ---------------------------------------------------------------------------
__global__ __launch_bounds__(256) void fused_kernel(
    const float* __restrict__ in,   // (N,P,S*M,2) f32
    const float* __restrict__ cof,  // (N,P,L)    f32, strictly positive
    float* __restrict__ out,        // (N,P,S*M,2) f32
    float* __restrict__ ht)         // (N,P,M,2)  f32
{
    const int b = blockIdx.x;
    const int t = threadIdx.x;

    if (b >= HT_BLKS) {
        const int sb = b - HT_BLKS;              // streaming block id

        // ---- issue all 8 loads first (independent of factor preamble) ----
        const f32x4* __restrict__ in4  = (const f32x4*)in + (size_t)sb * 2048;
        f32x4* __restrict__       out4 = (f32x4*)out      + (size_t)sb * 2048;
        f32x4 v[8];
#pragma unroll
        for (int k = 0; k < 8; ++k)
            v[k] = __builtin_nontemporal_load(&in4[k * 256 + t]);

        // ---- per-wave redundant factor computation (barrier-free) ----
        // lane = (j,l): j = which of the 4 (np,s) rows, l = tap index
        const int lane = t & 63;
        const int j    = lane >> 4;
        const int l    = lane & 15;
        const int id   = sb * 4 + j;             // flattened (np,s), < 8192
        const int np   = id >> 7;
        const int s    = id & (SS - 1);
        const float cofl   = cof[np * LTAPS + l];
        const float delay1 = (-100.0f / 3.0e8f) * logf(cofl);
        const float delay2 = (0.0005f / 14.0f) * (float)s;
        const float pc     = TWO_PI_F * 1000.0f * cosf((TWO_PI_F / 15.0f) * (float)l);
        const float ph     = pc * (delay1 + delay2);
        float sn, cs;
        sincosf(ph, &sn, &cs);
        float re = cofl * cs;
        float im = -cofl * sn;
        // reduce the 16 taps within each 16-lane group
#pragma unroll
        for (int w = 1; w < 16; w <<= 1) {
            re += __shfl_xor(re, w);
            im += __shfl_xor(im, w);
        }
        // broadcast the 4 group sums to every lane
        float fre[4], fim[4];
#pragma unroll
        for (int jj = 0; jj < 4; ++jj) {
            fre[jj] = __shfl(re, jj * 16);
            fim[jj] = __shfl(im, jj * 16);
        }

        // ---- multiply + store as loads return ----
#pragma unroll
        for (int k = 0; k < 8; ++k) {
            const int jj = k >> 1;               // 512 float4 per (np,s)
            f32x4 r;
            r.x = v[k].x * fre[jj] - v[k].y * fim[jj];
            r.y = v[k].x * fim[jj] + v[k].y * fre[jj];
            r.z = v[k].z * fre[jj] - v[k].w * fim[jj];
            r.w = v[k].z * fim[jj] + v[k].w * fre[jj];
            __builtin_nontemporal_store(r, &out4[k * 256 + t]);
        }
    } else {
        const int id = b * 256 + t;              // (np, k)
        const int np = id >> 10;
        const int k  = id & (MM - 1);
        float sn, cs;
        sincosf((TWO_PI_F / (float)MM) * (float)k, &sn, &cs);
        const float wr = cs, wi = -sn;           // w = exp(-2*pi*i*k/M)
        const float* __restrict__ c = cof + np * LTAPS;
        float hr = 0.0f, hi = 0.0f;              // H accumulator
        float cr = 1.0f, ci = 0.0f;              // w^l
#pragma unroll
        for (int l = 0; l < LTAPS; ++l) {
            const float cl = c[l];
            hr += cl * cr;
            hi += cl * ci;
            const float nr = cr * wr - ci * wi;
            const float ni = cr * wi + ci * wr;
            cr = nr; ci = ni;
        }
        float2* __restrict__ o = (float2*)ht;
        o[id] = make_float2(hr, hi);
    }
}

// ---------------------------------------------------------------------------
extern "C" void kernel_launch(void* const* d_in, const int* in_sizes, int n_in,
                              void* d_out, int out_size, void* d_ws, size_t ws_size,
                              hipStream_t stream)
{
    const float* in  = (const float*)d_in[0];   // input_ri (N,P,S*M,2)
    const float* cof = (const float*)d_in[1];   // cof (N,P,L)
    float* out = (float*)d_out;                              // out_ri first
    float* ht  = out + (size_t)NB * PB * SS * MM * 2;        // then H_t_ri

    hipLaunchKernelGGL(fused_kernel, dim3(HT_BLKS + STREAM_BLKS), dim3(256), 0, stream,
                       in, cof, out, ht);
}